// Round 17
// baseline (214.518 us; speedup 1.0000x reference)
//
#include <hip/hip_runtime.h>
#include <math.h>

// B,C,T = 32,1024,1024; beta=0.95; thr=1.0; sigma=10.5
#define B_     32
#define C_     1024
#define T_     1024
#define RT     92                 // tap radius (|d|>92 cannot flip any f32 spike; r2-r16)
#define KC     8                  // channels per thread
#define WOFF   (RT + KC - 1)      // 99: tap idx = d + 99, idx in [0,198]
#define NWT    200                // tap floats (50 quads)

// ---- pass 1 geometry: 256ch x 16t tile, 512 thr (16 t-lanes x 32 groups) ----
#define P1_CT   256
#define P1_TT   16
#define P1_NC   (P1_CT + 2*RT)    // 440 staged cols
#define P1_XSTR 444               // row stride (dwords), 16B-aligned rows
#define P1_NF4  (P1_NC * (P1_TT/4))  // 1760 staged float4s

// numpy-faithful f32 tap (identical op sequence; exp via correctly-rounded f64).
__device__ __forceinline__ float tap_value(float s, int d) {
    float u    = __fdiv_rn((float)d, s);
    float t1   = __fmul_rn(-0.5f, u);
    float t2   = __fmul_rn(t1, u);
    float e    = (float)exp((double)t2);
    float den  = __fmul_rn(s, sqrtf(6.2831854820251465f));
    float coef = __fdiv_rn(1.0f, den);
    return __fmul_rn(coef, e);
}

__global__ void init_w_kernel(const float* __restrict__ sigma, float* __restrict__ gw) {
    int i = threadIdx.x;
    if (i < NWT) {
        int d = i - WOFF;
        gw[i] = (d >= -RT && d <= RT) ? tap_value(sigma[0], d) : 0.0f;
    }
}

#define EL(v, i) ((i) == 0 ? (v).x : (i) == 1 ? (v).y : (i) == 2 ? (v).z : (v).w)
#define SEL5(il, T0, T1, T2, T3, T4)                                            \
    ((il) < 4 ? EL(T0, (il)) : (il) < 8 ? EL(T1, (il) - 4)                      \
     : (il) < 12 ? EL(T2, (il) - 8) : (il) < 16 ? EL(T3, (il) - 12)             \
     : EL(T4, (il) - 16))

// One source column (pass-relative cc): 8 FMAs, taps compile-time selected.
#define COL(XV, CC, T0, T1, T2, T3, T4)                                         \
    do {                                                                        \
        float x1_ = EL(XV, (CC) & 3);                                           \
        _Pragma("unroll")                                                       \
        for (int k = 0; k < KC; ++k) {                                          \
            const int il_ = (CC) + 7 - k;                                       \
            acc[k] = fmaf(SEL5(il_, T0, T1, T2, T3, T4), x1_, acc[k]);          \
        }                                                                       \
    } while (0)

// Tap quad Q (compile-time): 12 central quads in SGPRs, rest = uniform LDS b128.
#define GETQ(Q) (((Q) >= 19 && (Q) < 31) ? sgq[((Q) >= 19 && (Q) < 31) ? (Q) - 19 : 0] \
                                         : wt4[(Q)])

// Pass over cols QB*4..QB*4+11: issue next pass's operands, then 12 ascending cols.
#define PASSX(QB, T0, T1, T2, T3, T4, L0, L1, L2, XA, XB, XC, YA, YB, YC, DOLD) \
    do {                                                                        \
        if (DOLD) {                                                             \
            YA = xq[(QB) + 3]; YB = xq[(QB) + 4]; YC = xq[(QB) + 5];            \
            L0 = GETQ((QB) + 5); L1 = GETQ((QB) + 6); L2 = GETQ((QB) + 7);      \
        }                                                                       \
        COL(XA, 0, T0, T1, T2, T3, T4);  COL(XA, 1, T0, T1, T2, T3, T4);        \
        COL(XA, 2, T0, T1, T2, T3, T4);  COL(XA, 3, T0, T1, T2, T3, T4);        \
        COL(XB, 4, T0, T1, T2, T3, T4);  COL(XB, 5, T0, T1, T2, T3, T4);        \
        COL(XB, 6, T0, T1, T2, T3, T4);  COL(XB, 7, T0, T1, T2, T3, T4);        \
        COL(XC, 8, T0, T1, T2, T3, T4);  COL(XC, 9, T0, T1, T2, T3, T4);        \
        COL(XC, 10, T0, T1, T2, T3, T4); COL(XC, 11, T0, T1, T2, T3, T4);       \
    } while (0)

// ---- PASS 1: conv -> I (written to d_out as scratch). One shot per block.
// grid (4 ctiles, 64 ttiles, 32 b); block (16 t-lanes, 32 groups) = 512 thr.
// LDS 29.2 KB -> 4 blocks/CU = 32 waves/CU = 8 waves/SIMD (2x the fused TLP).
template <bool GW>
__global__ __launch_bounds__(512, 8) void snn_conv_I(
    const float* __restrict__ x, const float* __restrict__ sigma,
    const float* __restrict__ gw, float* __restrict__ out)
{
    __shared__ __align__(16) float xsT[P1_TT * P1_XSTR];  // 28416 B
    __shared__ __align__(16) float wtab[NWT];             //   800 B (total 29216)

    const int tx   = threadIdx.x;       // t lane 0..15
    const int ty   = threadIdx.y;       // group 0..31
    const int flat = ty * 16 + tx;
    const int c0   = blockIdx.x * P1_CT;
    const int t0   = blockIdx.y * P1_TT;
    const int b    = blockIdx.z;
    const int rb   = ty * KC;

    const float* xb = x + (size_t)b * ((size_t)C_ * T_);

    // ---- taps: from gw (bit-identical init kernel) or per-block compute ----
    if (flat < NWT) {
        if (GW) wtab[flat] = gw[flat];
        else {
            int d = flat - WOFF;
            wtab[flat] = (d >= -RT && d <= RT) ? tap_value(sigma[0], d) : 0.0f;
        }
    }

    // ---- stage x tile (transposed): col r = channel c0-RT+r, rows = t ----
#pragma unroll
    for (int i = 0; i < 4; ++i) {
        int e = flat + i * 512;
        if (e < P1_NF4) {
            int r = e >> 2, c4 = e & 3;
            int c = c0 - RT + r;
            float4 v = make_float4(0.f, 0.f, 0.f, 0.f);
            if (c >= 0 && c < C_)
                v = *(const float4*)(xb + (size_t)c * T_ + t0 + c4 * 4);
            xsT[(4 * c4 + 0) * P1_XSTR + r] = v.x;
            xsT[(4 * c4 + 1) * P1_XSTR + r] = v.y;
            xsT[(4 * c4 + 2) * P1_XSTR + r] = v.z;
            xsT[(4 * c4 + 3) * P1_XSTR + r] = v.w;
        }
    }
    __syncthreads();            // the ONLY barrier: tile + taps visible

    const float4* wt4 = (const float4*)wtab;
    // 12 central tap quads -> SGPRs (wave-uniform; readfirstlane forces scalar)
    float4 sgq[12];             // statically indexed only
#pragma unroll
    for (int i = 0; i < 12; ++i) {
        float4 q = wt4[19 + i];
        sgq[i].x = __int_as_float(__builtin_amdgcn_readfirstlane(__float_as_int(q.x)));
        sgq[i].y = __int_as_float(__builtin_amdgcn_readfirstlane(__float_as_int(q.y)));
        sgq[i].z = __int_as_float(__builtin_amdgcn_readfirstlane(__float_as_int(q.z)));
        sgq[i].w = __int_as_float(__builtin_amdgcn_readfirstlane(__float_as_int(q.w)));
    }

    float acc[KC];
#pragma unroll
    for (int k = 0; k < KC; ++k) acc[k] = 0.0f;

    const float4* xq = (const float4*)(xsT + tx * P1_XSTR + rb);

    // ---- prologue + 16 software-pipelined passes (ascending j, exact chain) ----
    float4 n0 = GETQ(0), n1 = GETQ(1), n2 = GETQ(2), n3 = GETQ(3), n4 = GETQ(4);
    float4 x0 = xq[0], x1 = xq[1], x2 = xq[2];
    float4 n5, n6, n7, x3, x4, x5;

    PASSX(0,  n0,n1,n2,n3,n4, n5,n6,n7, x0,x1,x2, x3,x4,x5, 1);
    PASSX(3,  n3,n4,n5,n6,n7, n0,n1,n2, x3,x4,x5, x0,x1,x2, 1);
    PASSX(6,  n6,n7,n0,n1,n2, n3,n4,n5, x0,x1,x2, x3,x4,x5, 1);
    PASSX(9,  n1,n2,n3,n4,n5, n6,n7,n0, x3,x4,x5, x0,x1,x2, 1);
    PASSX(12, n4,n5,n6,n7,n0, n1,n2,n3, x0,x1,x2, x3,x4,x5, 1);
    PASSX(15, n7,n0,n1,n2,n3, n4,n5,n6, x3,x4,x5, x0,x1,x2, 1);
    PASSX(18, n2,n3,n4,n5,n6, n7,n0,n1, x0,x1,x2, x3,x4,x5, 1);
    PASSX(21, n5,n6,n7,n0,n1, n2,n3,n4, x3,x4,x5, x0,x1,x2, 1);
    PASSX(24, n0,n1,n2,n3,n4, n5,n6,n7, x0,x1,x2, x3,x4,x5, 1);
    PASSX(27, n3,n4,n5,n6,n7, n0,n1,n2, x3,x4,x5, x0,x1,x2, 1);
    PASSX(30, n6,n7,n0,n1,n2, n3,n4,n5, x0,x1,x2, x3,x4,x5, 1);
    PASSX(33, n1,n2,n3,n4,n5, n6,n7,n0, x3,x4,x5, x0,x1,x2, 1);
    PASSX(36, n4,n5,n6,n7,n0, n1,n2,n3, x0,x1,x2, x3,x4,x5, 1);
    PASSX(39, n7,n0,n1,n2,n3, n4,n5,n6, x3,x4,x5, x0,x1,x2, 1);
    PASSX(42, n2,n3,n4,n5,n6, n7,n0,n1, x0,x1,x2, x3,x4,x5, 1);
    PASSX(45, n5,n6,n7,n0,n1, n2,n3,n4, x3,x4,x5, x0,x1,x2, 0);

    // ---- I = x - conv -> global (d_out as I-buffer; coalesced 64B/group) ----
    {
        float4 xo0 = xq[RT / 4];        // own x, cols rb+92..95
        float4 xo1 = xq[RT / 4 + 1];    // cols rb+96..99
        float Iv[KC] = {
            __fsub_rn(xo0.x, acc[0]), __fsub_rn(xo0.y, acc[1]),
            __fsub_rn(xo0.z, acc[2]), __fsub_rn(xo0.w, acc[3]),
            __fsub_rn(xo1.x, acc[4]), __fsub_rn(xo1.y, acc[5]),
            __fsub_rn(xo1.z, acc[6]), __fsub_rn(xo1.w, acc[7])};
        float* obase = out + ((size_t)b * C_ + (c0 + rb)) * T_ + t0 + tx;
#pragma unroll
        for (int k = 0; k < KC; ++k)
            obase[(size_t)k * T_] = Iv[k];
    }
}

// ---- PASS 2: LIF scan over I (in d_out), spikes overwrite in place.
// grid (16 ctiles, 32 b); block (64, 8). Proven v2/v4 structure.
__global__ __launch_bounds__(512) void snn_scan(float* __restrict__ out)
{
    __shared__ float Is[64 * 65];      // 16640 B; pitch 65 -> conflict-free scan

    const int tx   = threadIdx.x;      // 0..63
    const int ty   = threadIdx.y;      // 0..7
    const int flat = ty * 64 + tx;
    const int c0   = blockIdx.x * 64;
    const int b    = blockIdx.y;

    float* base = out + ((size_t)b * C_ + c0) * T_;

    float mem = 0.0f;                  // channel c0+tx (wave 0 lanes)
    float rc  = 0.0f;                  // carried reset (= previous spike)

#pragma unroll 1
    for (int kk = 0; kk < T_ / 64; ++kk) {
        // ---- stage I chunk [64ch][64t] (coalesced float4 reads) ----
#pragma unroll
        for (int i = 0; i < 2; ++i) {
            int e = flat + i * 512;
            int r = e >> 4, c4 = e & 15;
            float4 v = *(const float4*)(base + (size_t)r * T_ + kk * 64 + c4 * 4);
            Is[r * 65 + 4 * c4 + 0] = v.x;
            Is[r * 65 + 4 * c4 + 1] = v.y;
            Is[r * 65 + 4 * c4 + 2] = v.z;
            Is[r * 65 + 4 * c4 + 3] = v.w;
        }
        __syncthreads();        // I staged; all in-place reads of this chunk done

        // ---- scan (wave 0; lane = channel). reset == compare (established). ----
        if (ty == 0) {
            float m = mem, r = rc;
            float* orow = base + (size_t)tx * T_ + kk * 64;
#pragma unroll 4
            for (int q = 0; q < 16; ++q) {
                float4 s;
#pragma unroll
                for (int qq = 0; qq < 4; ++qq) {
                    float Ivv = Is[tx * 65 + 4 * q + qq];
                    m = __fsub_rn(__fadd_rn(__fmul_rn(0.95f, m), Ivv), r);
                    float sp = (m > 1.0f) ? 1.0f : 0.0f;
                    r = sp;
                    if (qq == 0) s.x = sp; else if (qq == 1) s.y = sp;
                    else if (qq == 2) s.z = sp; else s.w = sp;
                }
                *(float4*)(orow + 4 * q) = s;   // overwrites I (this chunk only)
            }
            mem = m; rc = r;
        }
        __syncthreads();        // scan reads done before next chunk's stage
    }
}

extern "C" void kernel_launch(void* const* d_in, const int* in_sizes, int n_in,
                              void* d_out, int out_size, void* d_ws, size_t ws_size,
                              hipStream_t stream) {
    const float* x     = (const float*)d_in[0];   // [32,1024,1024] f32
    const float* sigma = (const float*)d_in[1];   // [1] f32
    float* out = (float*)d_out;

    dim3 g1(C_ / P1_CT, T_ / P1_TT, B_);   // (4, 64, 32) = 8192 blocks
    dim3 b1(P1_TT, 32);                    // 512 threads
    dim3 g2(C_ / 64, B_);                  // (16, 32) = 512 blocks
    dim3 b2(64, 8);                        // 512 threads

    if (ws_size >= NWT * sizeof(float)) {
        float* gw = (float*)d_ws;
        init_w_kernel<<<1, 256, 0, stream>>>(sigma, gw);
        snn_conv_I<true><<<g1, b1, 0, stream>>>(x, sigma, gw, out);
    } else {
        snn_conv_I<false><<<g1, b1, 0, stream>>>(x, sigma, nullptr, out);
    }
    snn_scan<<<g2, b2, 0, stream>>>(out);
}

// Round 18
// 176.262 us; speedup vs baseline: 1.2170x; 1.2170x over previous
//
#include <hip/hip_runtime.h>
#include <math.h>

// B,C,T = 32,1024,1024; beta=0.95; thr=1.0; sigma=10.5
#define B_     32
#define C_     1024
#define T_     1024
#define RT     92                    // tap radius (|d|>92 cannot flip any f32 spike; r2-r17)
#define CT     64                    // channels per block
#define TT     64                    // time chunk
#define KC     8                     // channels per thread group
#define NTY    8                     // 8 waves, 512 threads
#define WOFF   (RT + KC - 1)         // 99: tap idx = d + 99, idx in [0,198]
#define NWT    200                   // tap floats (50 quads, rows 0..49 pads)
#define NCOLS  (CT + 2*RT)           // 248 staged channel columns
#define XSTR   252                   // xsT row stride (dwords); cols 248..251 = tap pad
#define ISTR   68                    // I-strip row stride (dwords): 16B-aligned rows
#define NF4    (NCOLS * (TT/4))      // 3968 staged float4s per chunk
#define NSQ0   19                    // first SGPR-resident tap quad
#define NSQN   12                    // 12 quads = 48 taps

// numpy-faithful f32 tap (identical op sequence; exp via correctly-rounded f64).
__device__ __forceinline__ float tap_value(float s, int d) {
    float u    = __fdiv_rn((float)d, s);
    float t1   = __fmul_rn(-0.5f, u);
    float t2   = __fmul_rn(t1, u);
    float e    = (float)exp((double)t2);
    float den  = __fmul_rn(s, sqrtf(6.2831854820251465f));
    float coef = __fdiv_rn(1.0f, den);
    return __fmul_rn(coef, e);
}

#define EL(v, i) ((i) == 0 ? (v).x : (i) == 1 ? (v).y : (i) == 2 ? (v).z : (v).w)
#define SEL5(il, T0, T1, T2, T3, T4)                                            \
    ((il) < 4 ? EL(T0, (il)) : (il) < 8 ? EL(T1, (il) - 4)                      \
     : (il) < 12 ? EL(T2, (il) - 8) : (il) < 16 ? EL(T3, (il) - 12)             \
     : EL(T4, (il) - 16))

// One source column (pass-relative cc): 8 FMAs, taps compile-time selected.
#define COL(XV, CC, T0, T1, T2, T3, T4)                                         \
    do {                                                                        \
        float x1_ = EL(XV, (CC) & 3);                                           \
        _Pragma("unroll")                                                       \
        for (int k = 0; k < KC; ++k) {                                          \
            const int il_ = (CC) + 7 - k;                                       \
            acc[k] = fmaf(SEL5(il_, T0, T1, T2, T3, T4), x1_, acc[k]);          \
        }                                                                       \
    } while (0)

// Tap quad Q: SGPR-resident for Q in [NSQ0, NSQ0+NSQN), else LDS pad read.
#define GETQ(Q)                                                                 \
    (((Q) >= NSQ0 && (Q) < NSQ0 + NSQN)                                         \
         ? sgq[((Q) >= NSQ0 && (Q) < NSQ0 + NSQN) ? (Q) - NSQ0 : 0]             \
         : TAPQ(Q))

// Pass over cols QB*4..QB*4+11: issue next pass's 3 x-quads + 3 tap-quads,
// then FENCE (sched_barrier 0x7: ALU may cross, memory may NOT) so the loads
// cannot sink into the 96-FMA block -> liveness forces register allocation,
// and the lgkmcnt wait for pass p+1 lands after pass p's FMAs.
#define PASSX(QB, T0, T1, T2, T3, T4, L0, L1, L2, XA, XB, XC, YA, YB, YC, DOLD) \
    do {                                                                        \
        if (DOLD) {                                                             \
            YA = xq[(QB) + 3]; YB = xq[(QB) + 4]; YC = xq[(QB) + 5];            \
            L0 = GETQ((QB) + 5); L1 = GETQ((QB) + 6); L2 = GETQ((QB) + 7);      \
            __builtin_amdgcn_sched_barrier(0x7);                                \
        }                                                                       \
        COL(XA, 0, T0, T1, T2, T3, T4);  COL(XA, 1, T0, T1, T2, T3, T4);        \
        COL(XA, 2, T0, T1, T2, T3, T4);  COL(XA, 3, T0, T1, T2, T3, T4);        \
        COL(XB, 4, T0, T1, T2, T3, T4);  COL(XB, 5, T0, T1, T2, T3, T4);        \
        COL(XB, 6, T0, T1, T2, T3, T4);  COL(XB, 7, T0, T1, T2, T3, T4);        \
        COL(XC, 8, T0, T1, T2, T3, T4);  COL(XC, 9, T0, T1, T2, T3, T4);        \
        COL(XC, 10, T0, T1, T2, T3, T4); COL(XC, 11, T0, T1, T2, T3, T4);       \
    } while (0)

// waves_per_eu(4,4): LDS caps at 2 blocks/CU = 4 waves/SIMD; declare it so the
// allocator's budget is 128 VGPRs, not the default 8-wave/64-reg target.
__global__ __launch_bounds__(512)
__attribute__((amdgpu_waves_per_eu(4, 4))) void snn_v18(
    const float* __restrict__ x, const float* __restrict__ sigma,
    float* __restrict__ out)
{
    __shared__ __align__(16) float xsT[TT * XSTR];       // 64512 B (incl. tap pads)
    __shared__ __align__(16) float IsS[NTY * KC * ISTR]; // 17408 B (total 81920 = 2/CU)

    const int tx   = threadIdx.x;      // t lane 0..63
    const int ty   = threadIdx.y;      // wave 0..7
    const int flat = ty * 64 + tx;
    const int b    = blockIdx.y;
    const int c0   = blockIdx.x * CT;
    const int rb   = ty * KC;

    const float* xb = x   + (size_t)b * ((size_t)C_ * T_);
    float*       ob = out + (size_t)b * ((size_t)C_ * T_);

    // ---- taps into xsT row pads (rows 0..49, cols 248..251) ----
    if (flat < NWT) {
        int d = flat - WOFF;
        xsT[(flat >> 2) * XSTR + 248 + (flat & 3)] =
            (d >= -RT && d <= RT) ? tap_value(sigma[0], d) : 0.0f;
    }

    // ---- register staging (proven path): (r = chan col, c4 = t-quad) ----
    float4 stg[2][4];                  // statically indexed only (rule #20)
    const int rB  = (flat >> 2);       // 0..127
    const int c4B = (flat & 3);        // 0..3

#define STAGE_LOAD(T0)                                                          \
    _Pragma("unroll")                                                           \
    for (int i1 = 0; i1 < 2; ++i1) {                                            \
        _Pragma("unroll")                                                       \
        for (int i2 = 0; i2 < 4; ++i2) {                                        \
            int r  = rB + 128 * i1;                                             \
            int c4 = c4B + 4 * i2;                                              \
            int c  = c0 - RT + r;                                               \
            float4 v = make_float4(0.f, 0.f, 0.f, 0.f);                         \
            if (r < NCOLS && c >= 0 && c < C_)                                  \
                v = *(const float4*)(xb + (size_t)c * T_ + (T0) + c4 * 4);      \
            stg[i1][i2] = v;                                                    \
        }                                                                       \
    }

#define STAGE_WRITE()                                                           \
    _Pragma("unroll")                                                           \
    for (int i1 = 0; i1 < 2; ++i1) {                                            \
        _Pragma("unroll")                                                       \
        for (int i2 = 0; i2 < 4; ++i2) {                                        \
            int r  = rB + 128 * i1;                                             \
            int c4 = c4B + 4 * i2;                                              \
            if (r < NCOLS) {                                                    \
                xsT[(4 * c4 + 0) * XSTR + r] = stg[i1][i2].x;                   \
                xsT[(4 * c4 + 1) * XSTR + r] = stg[i1][i2].y;                   \
                xsT[(4 * c4 + 2) * XSTR + r] = stg[i1][i2].z;                   \
                xsT[(4 * c4 + 3) * XSTR + r] = stg[i1][i2].w;                   \
            }                                                                   \
        }                                                                       \
    }

#define TAPQ(Q) (*(const float4*)(xsT + (Q) * XSTR + 248))

    STAGE_LOAD(0);
    __syncthreads();                   // taps visible to all waves

    // ---- 48 central taps -> SGPRs once (readfirstlane forces scalar) ----
    float4 sgq[NSQN];                  // statically indexed only
#pragma unroll
    for (int i = 0; i < NSQN; ++i) {
        float4 q = TAPQ(NSQ0 + i);
        sgq[i].x = __int_as_float(__builtin_amdgcn_readfirstlane(__float_as_int(q.x)));
        sgq[i].y = __int_as_float(__builtin_amdgcn_readfirstlane(__float_as_int(q.y)));
        sgq[i].z = __int_as_float(__builtin_amdgcn_readfirstlane(__float_as_int(q.z)));
        sgq[i].w = __int_as_float(__builtin_amdgcn_readfirstlane(__float_as_int(q.w)));
    }

    float mem = 0.0f;                  // channel c0+rb+tx (lanes tx<8)
    float rc  = 0.0f;                  // carried reset (= previous spike)
    float* strip = IsS + ty * (KC * ISTR);
    const float4* xq = (const float4*)(xsT + tx * XSTR + rb);

#pragma unroll 1
    for (int kk = 0; kk < T_ / TT; ++kk) {
        STAGE_WRITE();          // chunk kk -> xsT (waits its own vmcnt)
        __syncthreads();        // xsT ready for all waves

        if (kk < T_ / TT - 1) { STAGE_LOAD((kk + 1) * TT); }  // lands by next write

        float acc[KC];
#pragma unroll
        for (int k = 0; k < KC; ++k) acc[k] = 0.0f;

        // ---- prologue: pass-0 operands ----
        float4 n0 = GETQ(0), n1 = GETQ(1), n2 = GETQ(2), n3 = GETQ(3), n4 = GETQ(4);
        float4 x0 = xq[0], x1 = xq[1], x2 = xq[2];
        float4 n5, n6, n7, x3, x4, x5;

        // ---- 16 software-pipelined passes (rotating names; ascending j) ----
        PASSX(0,  n0,n1,n2,n3,n4, n5,n6,n7, x0,x1,x2, x3,x4,x5, 1);
        PASSX(3,  n3,n4,n5,n6,n7, n0,n1,n2, x3,x4,x5, x0,x1,x2, 1);
        PASSX(6,  n6,n7,n0,n1,n2, n3,n4,n5, x0,x1,x2, x3,x4,x5, 1);
        PASSX(9,  n1,n2,n3,n4,n5, n6,n7,n0, x3,x4,x5, x0,x1,x2, 1);
        PASSX(12, n4,n5,n6,n7,n0, n1,n2,n3, x0,x1,x2, x3,x4,x5, 1);
        PASSX(15, n7,n0,n1,n2,n3, n4,n5,n6, x3,x4,x5, x0,x1,x2, 1);
        PASSX(18, n2,n3,n4,n5,n6, n7,n0,n1, x0,x1,x2, x3,x4,x5, 1);
        PASSX(21, n5,n6,n7,n0,n1, n2,n3,n4, x3,x4,x5, x0,x1,x2, 1);
        PASSX(24, n0,n1,n2,n3,n4, n5,n6,n7, x0,x1,x2, x3,x4,x5, 1);
        PASSX(27, n3,n4,n5,n6,n7, n0,n1,n2, x3,x4,x5, x0,x1,x2, 1);
        PASSX(30, n6,n7,n0,n1,n2, n3,n4,n5, x0,x1,x2, x3,x4,x5, 1);
        PASSX(33, n1,n2,n3,n4,n5, n6,n7,n0, x3,x4,x5, x0,x1,x2, 1);
        PASSX(36, n4,n5,n6,n7,n0, n1,n2,n3, x0,x1,x2, x3,x4,x5, 1);
        PASSX(39, n7,n0,n1,n2,n3, n4,n5,n6, x3,x4,x5, x0,x1,x2, 1);
        PASSX(42, n2,n3,n4,n5,n6, n7,n0,n1, x0,x1,x2, x3,x4,x5, 1);
        PASSX(45, n5,n6,n7,n0,n1, n2,n3,n4, x3,x4,x5, x0,x1,x2, 0);

        // I = x - conv -> wave-local strip (no cross-wave hazard)
        {
            float4 xo0 = xq[RT / 4];        // own x, cols rb+92..95
            float4 xo1 = xq[RT / 4 + 1];    // cols rb+96..99
            strip[0 * ISTR + tx] = __fsub_rn(xo0.x, acc[0]);
            strip[1 * ISTR + tx] = __fsub_rn(xo0.y, acc[1]);
            strip[2 * ISTR + tx] = __fsub_rn(xo0.z, acc[2]);
            strip[3 * ISTR + tx] = __fsub_rn(xo0.w, acc[3]);
            strip[4 * ISTR + tx] = __fsub_rn(xo1.x, acc[4]);
            strip[5 * ISTR + tx] = __fsub_rn(xo1.y, acc[5]);
            strip[6 * ISTR + tx] = __fsub_rn(xo1.z, acc[6]);
            strip[7 * ISTR + tx] = __fsub_rn(xo1.w, acc[7]);
        }

        // ---- wave-local LIF scan (lanes tx<8; channel c0+rb+tx) ----
        // reset = RN(soft + RN(1-soft)) == 1.0f exactly for soft in (0,0.5):
        // the atan surrogate is bit-exactly a compare; reset_{t+1} == spike_t.
        if (tx < KC) {
            float m = mem, r = rc;
            const float4* srow4 = (const float4*)(strip + tx * ISTR);
            float* orow = ob + (size_t)(c0 + rb + tx) * T_ + (size_t)kk * TT;
#pragma unroll 4
            for (int q = 0; q < TT / 4; ++q) {
                float4 Iq = srow4[q];
                float4 s;
#pragma unroll
                for (int qq = 0; qq < 4; ++qq) {
                    float Ivv = EL(Iq, qq);
                    m = __fsub_rn(__fadd_rn(__fmul_rn(0.95f, m), Ivv), r);
                    float sp = (m > 1.0f) ? 1.0f : 0.0f;
                    r = sp;
                    if (qq == 0) s.x = sp; else if (qq == 1) s.y = sp;
                    else if (qq == 2) s.z = sp; else s.w = sp;
                }
                *(float4*)(orow + 4 * q) = s;
            }
            mem = m; rc = r;
        }
        __syncthreads();        // xsT WAR: all waves' reads done before next write
    }
#undef STAGE_LOAD
#undef STAGE_WRITE
#undef TAPQ
}

extern "C" void kernel_launch(void* const* d_in, const int* in_sizes, int n_in,
                              void* d_out, int out_size, void* d_ws, size_t ws_size,
                              hipStream_t stream) {
    const float* x     = (const float*)d_in[0];   // [32,1024,1024] f32
    const float* sigma = (const float*)d_in[1];   // [1] f32
    float* out = (float*)d_out;

    dim3 grid(C_ / CT, B_);   // (16, 32) = 512 blocks, 2/CU
    dim3 block(64, NTY);      // 512 threads, 8 waves

    snn_v18<<<grid, block, 0, stream>>>(x, sigma, out);
}

// Round 19
// 166.333 us; speedup vs baseline: 1.2897x; 1.0597x over previous
//
#include <hip/hip_runtime.h>
#include <math.h>

// B,C,T = 32,1024,1024; beta=0.95; thr=1.0; sigma=10.5
#define B_     32
#define C_     1024
#define T_     1024
#define RT     92                 // tap radius (|d|>92 cannot flip any f32 spike; r2-r18)
#define KC     8                  // channels per thread
#define WOFF   (RT + KC - 1)      // 99: tap idx = d + 99, idx in [0,198]
#define NWT    200                // tap floats (50 quads)
#define NCOLS  248                // staged channel columns (64 + 2*92)
#define XSTR   252                // buf row stride (dwords); cols 248..251 = tap pad
#define TTC    32                 // chunk length (time)
#define ISTR   33                 // strip row stride (dwords): conflict-free scan
#define NQ4    (NCOLS * (TTC/4))  // 1984 staged float4s per chunk
#define NSQ0   19                 // first SGPR-resident tap quad
#define NSQN   12                 // 12 quads = 48 taps

// numpy-faithful f32 tap (identical op sequence; exp via correctly-rounded f64).
__device__ __forceinline__ float tap_value(float s, int d) {
    float u    = __fdiv_rn((float)d, s);
    float t1   = __fmul_rn(-0.5f, u);
    float t2   = __fmul_rn(t1, u);
    float e    = (float)exp((double)t2);
    float den  = __fmul_rn(s, sqrtf(6.2831854820251465f));
    float coef = __fdiv_rn(1.0f, den);
    return __fmul_rn(coef, e);
}

#define EL(v, i) ((i) == 0 ? (v).x : (i) == 1 ? (v).y : (i) == 2 ? (v).z : (v).w)
#define SEL5(il, T0, T1, T2, T3, T4)                                            \
    ((il) < 4 ? EL(T0, (il)) : (il) < 8 ? EL(T1, (il) - 4)                      \
     : (il) < 12 ? EL(T2, (il) - 8) : (il) < 16 ? EL(T3, (il) - 12)             \
     : EL(T4, (il) - 16))

// One source column (pass-relative cc): 8 FMAs, taps compile-time selected.
#define COL(XV, CC, T0, T1, T2, T3, T4)                                         \
    do {                                                                        \
        float x1_ = EL(XV, (CC) & 3);                                           \
        _Pragma("unroll")                                                       \
        for (int k = 0; k < KC; ++k) {                                          \
            const int il_ = (CC) + 7 - k;                                       \
            acc[k] = fmaf(SEL5(il_, T0, T1, T2, T3, T4), x1_, acc[k]);          \
        }                                                                       \
    } while (0)

// Tap quad Q (compile-time): quads 0..31 live in xsA row pads, 32..49 in xsB
// row pads; 12 central quads overridden to SGPR residence.
#define TAPQ(Q)                                                                 \
    (*(const float4*)(((Q) < 32 ? xsA + (Q) * XSTR : xsB + ((Q) - 32) * XSTR) + 248))
#define GETQ(Q)                                                                 \
    (((Q) >= NSQ0 && (Q) < NSQ0 + NSQN)                                         \
         ? sgq[((Q) >= NSQ0 && (Q) < NSQ0 + NSQN) ? (Q) - NSQ0 : 0]             \
         : TAPQ(Q))

// Pass over cols QB*4..QB*4+11: issue next pass's operands, then 12 ascending cols.
#define PASSX(QB, T0, T1, T2, T3, T4, L0, L1, L2, XA, XB, XC, YA, YB, YC, DOLD) \
    do {                                                                        \
        if (DOLD) {                                                             \
            YA = xq[(QB) + 3]; YB = xq[(QB) + 4]; YC = xq[(QB) + 5];            \
            L0 = GETQ((QB) + 5); L1 = GETQ((QB) + 6); L2 = GETQ((QB) + 7);      \
        }                                                                       \
        COL(XA, 0, T0, T1, T2, T3, T4);  COL(XA, 1, T0, T1, T2, T3, T4);        \
        COL(XA, 2, T0, T1, T2, T3, T4);  COL(XA, 3, T0, T1, T2, T3, T4);        \
        COL(XB, 4, T0, T1, T2, T3, T4);  COL(XB, 5, T0, T1, T2, T3, T4);        \
        COL(XB, 6, T0, T1, T2, T3, T4);  COL(XB, 7, T0, T1, T2, T3, T4);        \
        COL(XC, 8, T0, T1, T2, T3, T4);  COL(XC, 9, T0, T1, T2, T3, T4);        \
        COL(XC, 10, T0, T1, T2, T3, T4); COL(XC, 11, T0, T1, T2, T3, T4);       \
    } while (0)

// Producer/consumer wave-role split by chunk parity: in step m, group
// parity(m) convs chunk m (FMA-heavy) while the other group scans chunk m-1
// (wave 0) and stages chunk m+1 (waves 1-3) -> DS/VMEM work of one group
// overlaps the FMA stream of the other on every SIMD (convoy broken).
__global__ __launch_bounds__(512, 4) void snn_v19(
    const float* __restrict__ x, const float* __restrict__ sigma,
    float* __restrict__ out)
{
    __shared__ __align__(16) float xsA[TTC * XSTR];   // 32256 B (+ tap pads)
    __shared__ __align__(16) float xsB[TTC * XSTR];   // 32256 B (+ tap pads)
    __shared__ __align__(16) float stripA[64 * ISTR]; //  8448 B
    __shared__ __align__(16) float stripB[64 * ISTR]; //  8448 B
    __shared__ float mem_lds[64];                     //   256 B (total 81664)

    const int tx   = threadIdx.x;       // lane 0..63
    const int ty   = threadIdx.y;       // wave 0..7
    const int flat = ty * 64 + tx;
    const int g    = ty >> 2;           // group: 0=A (even chunks), 1=B (odd)
    const int wg   = ty & 3;            // wave within group
    const int b    = blockIdx.y;
    const int c0   = blockIdx.x * 64;

    const float* xb = x   + (size_t)b * ((size_t)C_ * T_);
    float*       ob = out + (size_t)b * ((size_t)C_ * T_);

    // ---- prologue: taps into buf pads, mem init, stage chunk 0 (all waves) ----
    if (flat < NWT) {
        int d = flat - WOFF;
        float w = (d >= -RT && d <= RT) ? tap_value(sigma[0], d) : 0.0f;
        int q = flat >> 2, e = flat & 3;
        float* dst = (q < 32) ? (xsA + q * XSTR + 248 + e)
                              : (xsB + (q - 32) * XSTR + 248 + e);
        *dst = w;
    }
    if (flat < 64) mem_lds[flat] = 0.0f;
#pragma unroll
    for (int i = 0; i < 4; ++i) {       // chunk 0 -> xsA (1984 quads / 512 thr)
        int e = flat + i * 512;
        if (e < NQ4) {
            int r = e >> 3, c4 = e & 7;
            int c = c0 - RT + r;
            float4 v = make_float4(0.f, 0.f, 0.f, 0.f);
            if (c >= 0 && c < C_)
                v = *(const float4*)(xb + (size_t)c * T_ + c4 * 4);
            xsA[(4 * c4 + 0) * XSTR + r] = v.x;
            xsA[(4 * c4 + 1) * XSTR + r] = v.y;
            xsA[(4 * c4 + 2) * XSTR + r] = v.z;
            xsA[(4 * c4 + 3) * XSTR + r] = v.w;
        }
    }
    __syncthreads();

    // ---- 48 central taps -> SGPRs once (readfirstlane forces scalar) ----
    float4 sgq[NSQN];                   // statically indexed only
#pragma unroll
    for (int i = 0; i < NSQN; ++i) {
        float4 q = TAPQ(NSQ0 + i);
        sgq[i].x = __int_as_float(__builtin_amdgcn_readfirstlane(__float_as_int(q.x)));
        sgq[i].y = __int_as_float(__builtin_amdgcn_readfirstlane(__float_as_int(q.y)));
        sgq[i].z = __int_as_float(__builtin_amdgcn_readfirstlane(__float_as_int(q.z)));
        sgq[i].w = __int_as_float(__builtin_amdgcn_readfirstlane(__float_as_int(q.w)));
    }

    const int tloc = tx & 31;           // conv: time lane
    const int rb   = wg * 16 + (tx >> 5) * 8;   // conv: first channel
    float* bufg    = (g == 0) ? xsA : xsB;
    float* stripg  = (g == 0) ? stripA : stripB;
    const float4* xq = (const float4*)(bufg + tloc * XSTR + rb);

#pragma unroll 1
    for (int m = 0; m <= 32; ++m) {
        if (m <= 31 && g == (m & 1)) {
            // ================= CONV chunk m (my group's buffer) =================
            float acc[KC];
#pragma unroll
            for (int k = 0; k < KC; ++k) acc[k] = 0.0f;

            float4 n0 = GETQ(0), n1 = GETQ(1), n2 = GETQ(2), n3 = GETQ(3), n4 = GETQ(4);
            float4 x0 = xq[0], x1 = xq[1], x2 = xq[2];
            float4 n5, n6, n7, x3, x4, x5;

            PASSX(0,  n0,n1,n2,n3,n4, n5,n6,n7, x0,x1,x2, x3,x4,x5, 1);
            PASSX(3,  n3,n4,n5,n6,n7, n0,n1,n2, x3,x4,x5, x0,x1,x2, 1);
            PASSX(6,  n6,n7,n0,n1,n2, n3,n4,n5, x0,x1,x2, x3,x4,x5, 1);
            PASSX(9,  n1,n2,n3,n4,n5, n6,n7,n0, x3,x4,x5, x0,x1,x2, 1);
            PASSX(12, n4,n5,n6,n7,n0, n1,n2,n3, x0,x1,x2, x3,x4,x5, 1);
            PASSX(15, n7,n0,n1,n2,n3, n4,n5,n6, x3,x4,x5, x0,x1,x2, 1);
            PASSX(18, n2,n3,n4,n5,n6, n7,n0,n1, x0,x1,x2, x3,x4,x5, 1);
            PASSX(21, n5,n6,n7,n0,n1, n2,n3,n4, x3,x4,x5, x0,x1,x2, 1);
            PASSX(24, n0,n1,n2,n3,n4, n5,n6,n7, x0,x1,x2, x3,x4,x5, 1);
            PASSX(27, n3,n4,n5,n6,n7, n0,n1,n2, x3,x4,x5, x0,x1,x2, 1);
            PASSX(30, n6,n7,n0,n1,n2, n3,n4,n5, x0,x1,x2, x3,x4,x5, 1);
            PASSX(33, n1,n2,n3,n4,n5, n6,n7,n0, x3,x4,x5, x0,x1,x2, 1);
            PASSX(36, n4,n5,n6,n7,n0, n1,n2,n3, x0,x1,x2, x3,x4,x5, 1);
            PASSX(39, n7,n0,n1,n2,n3, n4,n5,n6, x3,x4,x5, x0,x1,x2, 1);
            PASSX(42, n2,n3,n4,n5,n6, n7,n0,n1, x0,x1,x2, x3,x4,x5, 1);
            PASSX(45, n5,n6,n7,n0,n1, n2,n3,n4, x3,x4,x5, x0,x1,x2, 0);

            // I = x - conv -> my group's strip [ch][t]
            float4 xo0 = xq[RT / 4];        // own x, cols rb+92..95
            float4 xo1 = xq[RT / 4 + 1];    // cols rb+96..99
            stripg[(rb + 0) * ISTR + tloc] = __fsub_rn(xo0.x, acc[0]);
            stripg[(rb + 1) * ISTR + tloc] = __fsub_rn(xo0.y, acc[1]);
            stripg[(rb + 2) * ISTR + tloc] = __fsub_rn(xo0.z, acc[2]);
            stripg[(rb + 3) * ISTR + tloc] = __fsub_rn(xo0.w, acc[3]);
            stripg[(rb + 4) * ISTR + tloc] = __fsub_rn(xo1.x, acc[4]);
            stripg[(rb + 5) * ISTR + tloc] = __fsub_rn(xo1.y, acc[5]);
            stripg[(rb + 6) * ISTR + tloc] = __fsub_rn(xo1.z, acc[6]);
            stripg[(rb + 7) * ISTR + tloc] = __fsub_rn(xo1.w, acc[7]);
        } else {
            if (wg == 0) {
                // ============ SCAN chunk m-1 (my group's strip, all 64 ch) ============
                // reset r = (stored mem > 1) == last spike of prev chunk (exact).
                if (m >= 1 && g == ((m - 1) & 1)) {
                    float mv = mem_lds[tx];
                    float r  = (mv > 1.0f) ? 1.0f : 0.0f;
                    const float* srow = stripg + tx * ISTR;
                    float* orow = ob + (size_t)(c0 + tx) * T_ + (size_t)(m - 1) * TTC;
#pragma unroll
                    for (int q = 0; q < TTC / 4; ++q) {
                        float4 s;
#pragma unroll
                        for (int qq = 0; qq < 4; ++qq) {
                            float Ivv = srow[4 * q + qq];
                            mv = __fsub_rn(__fadd_rn(__fmul_rn(0.95f, mv), Ivv), r);
                            float sp = (mv > 1.0f) ? 1.0f : 0.0f;
                            r = sp;
                            if (qq == 0) s.x = sp; else if (qq == 1) s.y = sp;
                            else if (qq == 2) s.z = sp; else s.w = sp;
                        }
                        *(float4*)(orow + 4 * q) = s;
                    }
                    mem_lds[tx] = mv;
                }
            } else {
                // ============ STAGE chunk m+1 into my group's buffer ============
                if (m + 1 <= 31) {
                    const int t0s  = (m + 1) * TTC;
                    const int wthr = (wg - 1) * 64 + tx;    // 0..191
                    float4 vv[11];                           // static idx (rule #20)
#pragma unroll
                    for (int i = 0; i < 11; ++i) {
                        int e = wthr + i * 192;
                        float4 v = make_float4(0.f, 0.f, 0.f, 0.f);
                        if (e < NQ4) {
                            int r = e >> 3, c4 = e & 7;
                            int c = c0 - RT + r;
                            if (c >= 0 && c < C_)
                                v = *(const float4*)(xb + (size_t)c * T_ + t0s + c4 * 4);
                        }
                        vv[i] = v;
                    }
#pragma unroll
                    for (int i = 0; i < 11; ++i) {
                        int e = wthr + i * 192;
                        if (e < NQ4) {
                            int r = e >> 3, c4 = e & 7;
                            bufg[(4 * c4 + 0) * XSTR + r] = vv[i].x;
                            bufg[(4 * c4 + 1) * XSTR + r] = vv[i].y;
                            bufg[(4 * c4 + 2) * XSTR + r] = vv[i].z;
                            bufg[(4 * c4 + 3) * XSTR + r] = vv[i].w;
                        }
                    }
                }
            }
        }
        __syncthreads();    // step boundary: buffers/strips/mem handoff ordered
    }
}

extern "C" void kernel_launch(void* const* d_in, const int* in_sizes, int n_in,
                              void* d_out, int out_size, void* d_ws, size_t ws_size,
                              hipStream_t stream) {
    const float* x     = (const float*)d_in[0];   // [32,1024,1024] f32
    const float* sigma = (const float*)d_in[1];   // [1] f32
    float* out = (float*)d_out;

    dim3 grid(C_ / 64, B_);   // (16, 32) = 512 blocks, 2/CU
    dim3 block(64, 8);        // 512 threads, 8 waves (A: 0-3, B: 4-7)

    snn_v19<<<grid, block, 0, stream>>>(x, sigma, out);
}